// Round 7
// baseline (142.933 us; speedup 1.0000x reference)
//
#include <hip/hip_runtime.h>
#include <math.h>

// Problem constants (fixed by setup_inputs)
#define NWORDS 8192
#define LW     24
#define VOC    128
#define DIM    512
#define NH     8
#define DKH    64
#define GNAMES 2048
#define F2     256

// stage-1 fused output layout (floats): [EQ 65536 | EK 65536 | EV 65536 | WF 262144]
#define S1_LEN 458752

// =================== double-buffered 64x64 fp32 GEMM body ====================
// 256 threads, BK=16, 4x4 register tile, one barrier per K-step.
// K_ is used as lda, N_ as ldb only.
#define GEMM_BODY(A_, B_, K_, N_, m0_, n0_, kbeg_, kchunk_)                         \
  __shared__ float As[2][16][68];                                                   \
  __shared__ float Bs[2][16][68];                                                   \
  const int t = threadIdx.x, tx = t & 15, ty = t >> 4;                              \
  float acc[4][4] = {};                                                             \
  float ra[4], rb[4];                                                               \
  _Pragma("unroll")                                                                 \
  for (int i = 0; i < 4; ++i) { int idx = t + 256 * i;                              \
    ra[i] = A_[(size_t)(m0_ + (idx >> 4)) * K_ + kbeg_ + (idx & 15)]; }             \
  _Pragma("unroll")                                                                 \
  for (int i = 0; i < 4; ++i) { int idx = t + 256 * i;                              \
    rb[i] = B_[(size_t)(kbeg_ + (idx >> 6)) * N_ + n0_ + (idx & 63)]; }             \
  _Pragma("unroll")                                                                 \
  for (int i = 0; i < 4; ++i) { int idx = t + 256 * i; As[0][idx & 15][idx >> 4] = ra[i]; } \
  _Pragma("unroll")                                                                 \
  for (int i = 0; i < 4; ++i) { int idx = t + 256 * i; Bs[0][idx >> 6][idx & 63] = rb[i]; } \
  __syncthreads();                                                                  \
  int buf = 0;                                                                      \
  for (int k0 = kbeg_; k0 < kbeg_ + kchunk_; k0 += 16) {                            \
    const bool more = (k0 + 16 < kbeg_ + kchunk_);                                  \
    if (more) {                                                                     \
      _Pragma("unroll")                                                             \
      for (int i = 0; i < 4; ++i) { int idx = t + 256 * i;                          \
        ra[i] = A_[(size_t)(m0_ + (idx >> 4)) * K_ + (k0 + 16) + (idx & 15)]; }     \
      _Pragma("unroll")                                                             \
      for (int i = 0; i < 4; ++i) { int idx = t + 256 * i;                          \
        rb[i] = B_[(size_t)(k0 + 16 + (idx >> 6)) * N_ + n0_ + (idx & 63)]; }       \
    }                                                                               \
    _Pragma("unroll")                                                               \
    for (int k = 0; k < 16; ++k) {                                                  \
      float a[4], b[4];                                                             \
      _Pragma("unroll")                                                             \
      for (int i = 0; i < 4; ++i) a[i] = As[buf][k][ty * 4 + i];                    \
      _Pragma("unroll")                                                             \
      for (int j = 0; j < 4; ++j) b[j] = Bs[buf][k][tx * 4 + j];                    \
      _Pragma("unroll")                                                             \
      for (int i = 0; i < 4; ++i)                                                   \
        _Pragma("unroll")                                                           \
        for (int j = 0; j < 4; ++j) acc[i][j] += a[i] * b[j];                       \
    }                                                                               \
    if (more) {                                                                     \
      _Pragma("unroll")                                                             \
      for (int i = 0; i < 4; ++i) { int idx = t + 256 * i; As[buf ^ 1][idx & 15][idx >> 4] = ra[i]; } \
      _Pragma("unroll")                                                             \
      for (int i = 0; i < 4; ++i) { int idx = t + 256 * i; Bs[buf ^ 1][idx >> 6][idx & 63] = rb[i]; } \
      __syncthreads();                                                              \
      buf ^= 1;                                                                     \
    }                                                                               \
  }

// ---- stage-1 fused GEMM: EQ/EK/EV (128x512) + WF=Wo@W1 (512x512), all K=512 ----
template<int NSPLIT>
__global__ __launch_bounds__(256) void k_stage1(const float* __restrict__ emb,
                                                const float* __restrict__ Wq,
                                                const float* __restrict__ Wk,
                                                const float* __restrict__ Wv,
                                                const float* __restrict__ Wo,
                                                const float* __restrict__ W1,
                                                float* __restrict__ P) {
  const int tid = blockIdx.x, s = blockIdx.y;
  const float *A, *B;
  int coff, m0, n0;
  if (tid < 48) {
    const int g = tid >> 4, mt = tid & 15;
    A = emb;
    B = (g == 0) ? Wq : ((g == 1) ? Wk : Wv);
    coff = g * 65536;
    m0 = (mt >> 3) * 64; n0 = (mt & 7) * 64;
  } else {
    const int id = tid - 48;
    A = Wo; B = W1; coff = 3 * 65536;
    m0 = (id >> 3) * 64; n0 = (id & 7) * 64;
  }
  const int kchunk = 512 / NSPLIT, kbeg = s * kchunk;
  GEMM_BODY(A, B, 512, 512, m0, n0, kbeg, kchunk)
  float* Cp = P + (size_t)s * S1_LEN + coff;
  #pragma unroll
  for (int i = 0; i < 4; ++i) {
    float4 v = make_float4(acc[i][0], acc[i][1], acc[i][2], acc[i][3]);
    *(float4*)&Cp[(size_t)(m0 + ty * 4 + i) * 512 + n0 + tx * 4] = v;
  }
}

// ---- generic GEMM: C = A@B partials over gridDim.z ----
template<int ACT>
__global__ __launch_bounds__(256) void k_gemm64(const float* __restrict__ A,
                                                const float* __restrict__ B,
                                                float* __restrict__ C,
                                                int M, int N, int K, int kchunk) {
  const int m0 = blockIdx.y * 64, n0 = blockIdx.x * 64;
  const int kbeg = blockIdx.z * kchunk;
  GEMM_BODY(A, B, K, N, m0, n0, kbeg, kchunk)
  float* Cp = C + (size_t)blockIdx.z * M * N;
  #pragma unroll
  for (int i = 0; i < 4; ++i) {
    float4 v = make_float4(acc[i][0], acc[i][1], acc[i][2], acc[i][3]);
    if (ACT) { v.x = tanhf(v.x); v.y = tanhf(v.y); v.z = tanhf(v.z); v.w = tanhf(v.w); }
    *(float4*)&Cp[(size_t)(m0 + ty * 4 + i) * N + n0 + tx * 4] = v;
  }
}

// ---- name-pool GEMM: NP[m, h*64+n] = sum_c Wn[m][h*128+c] * EV[c][h*64+n] ----
__global__ __launch_bounds__(256) void k_npool(const float* __restrict__ Wn,
                                               const float* __restrict__ EV,
                                               float* __restrict__ NP) {
  const int m0 = blockIdx.x * 64, h = blockIdx.y;
  const float* A2 = Wn + (size_t)m0 * 1024 + h * 128;   // lda 1024
  const float* B2 = EV + h * 64;                        // ldb 512
  GEMM_BODY(A2, B2, 1024, 512, 0, 0, 0, 128)
  #pragma unroll
  for (int i = 0; i < 4; ++i) {
    float4 v = make_float4(acc[i][0], acc[i][1], acc[i][2], acc[i][3]);
    *(float4*)&NP[(size_t)(m0 + ty * 4 + i) * 512 + h * 64 + tx * 4] = v;
  }
}

// ---- sum S partial buffers, optional tanh ----
template<int ACT, int S>
__global__ __launch_bounds__(256) void k_reduce(const float* __restrict__ P,
                                                float* __restrict__ O,
                                                int len4, int stride4) {
  const int i = blockIdx.x * 256 + threadIdx.x;
  if (i >= len4) return;
  const float4* P4 = (const float4*)P;
  float4 a = P4[i];
  #pragma unroll
  for (int s = 1; s < S; ++s) {
    float4 b = P4[(size_t)s * stride4 + i];
    a.x += b.x; a.y += b.y; a.z += b.z; a.w += b.w;
  }
  if (ACT) { a.x = tanhf(a.x); a.y = tanhf(a.y); a.z = tanhf(a.z); a.w = tanhf(a.w); }
  ((float4*)O)[i] = a;
}

// ---- exp(qk) table, zeroed on pad rows/cols: ETAB[c1][c2][h] ----
__global__ __launch_bounds__(128) void k_qk_tab(const float* __restrict__ EQ,
                                                const float* __restrict__ EK,
                                                float* __restrict__ etab) {
  const int c1 = blockIdx.x, h = blockIdx.y, c2 = threadIdx.x;
  __shared__ float qrow[DKH];
  if (threadIdx.x < DKH) qrow[threadIdx.x] = EQ[c1 * DIM + h * DKH + threadIdx.x];
  __syncthreads();
  const float* krow = EK + c2 * DIM + h * DKH;
  float acc = 0.f;
  #pragma unroll
  for (int d = 0; d < DKH; ++d) acc += qrow[d] * krow[d];
  float e = (c1 != 0 && c2 != 0) ? __expf(acc * 0.125f) : 0.f;
  etab[((size_t)c1 * VOC + c2) * NH + h] = e;
}

// ---- exclusive scan of n_words ----
__global__ __launch_bounds__(256) void k_scan(const int* __restrict__ nw, int* __restrict__ offs) {
  __shared__ int part[256];
  const int t = threadIdx.x;
  int v[8]; int s = 0;
  #pragma unroll
  for (int i = 0; i < 8; ++i) { v[i] = nw[t * 8 + i]; s += v[i]; }
  part[t] = s;
  __syncthreads();
  if (t == 0) {
    int a = 0;
    for (int i = 0; i < 256; ++i) { int x = part[i]; part[i] = a; a += x; }
    offs[GNAMES] = a;
  }
  __syncthreads();
  int a = part[t];
  #pragma unroll
  for (int i = 0; i < 8; ++i) { offs[t * 8 + i] = a; a += v[i]; }
}

// ---- attention-mass histogram per name: Wn[g][h][c] ----
// Block = name, 768 threads = 12 waves = 4 words x 3 q-thirds. Each wave:
// 8 q x 8 h = 64 lanes, exactly ONE (q,h) per lane -> one gather chain, one
// denominator, minimal registers. Word chars held in lane registers
// (lane l = char at position l), distributed by __shfl. Cross-q reduce =
// 3x shfl_xor over lane bits 3..5; lane ql==0 scatters atomicAdd into
// bins[ck][h] (consecutive banks, no LDS conflicts).
__global__ __launch_bounds__(768) void k_bins(const int* __restrict__ inputs,
                                              const int* __restrict__ offs,
                                              const float* __restrict__ etab,
                                              float* __restrict__ Wn) {
  const int g = blockIdx.x, t = threadIdx.x;
  const int wv = t >> 6, l = t & 63;
  const int wd = wv >> 2;          // 0..2: q-third  (12 waves = 3 thirds x 4 words)
  const int qt = wv & 3;           // 0..3: word     (wave-uniform decode below)
  const int h = l & 7, ql = l >> 3;
  const int q = wd * 8 + ql;       // q in 0..23
  const int o0 = offs[g], o1 = offs[g + 1];
  const int nw = o1 - o0;
  __shared__ float bins[VOC * NH]; // [c][h], 4 KB

  for (int i = t; i < VOC * NH; i += 768) bins[i] = 0.f;
  __syncthreads();

  if (qt < nw) {
    const int wi = o0 + qt;
    int c_l = (l < LW) ? inputs[(size_t)wi * LW + l] : 0;
    unsigned long long mk = __ballot(c_l != 0);
    int cnt = __popcll(mk);
    float invc = cnt ? 1.f / (float)cnt : 0.f;

    const int cq = __shfl(c_l, q);
    const int off0 = (cq << 10) + h;

    // pass 1: per-(q,h) softmax denominator (pad rows/cols are 0 in table)
    float d = 0.f;
    #pragma unroll
    for (int kp = 0; kp < LW; ++kp) {
      int ck = __shfl(c_l, kp);
      d += etab[off0 + (ck << 3)];
    }
    const float iq = cq ? invc / d : 0.f;

    // pass 2: re-gather (cache-hot), weight, reduce over 8 q's, scatter
    #pragma unroll
    for (int kp = 0; kp < LW; ++kp) {
      int ck = __shfl(c_l, kp);    // wave-uniform
      if (ck) {
        float v = etab[off0 + (ck << 3)] * iq;
        v += __shfl_xor(v, 8);
        v += __shfl_xor(v, 16);
        v += __shfl_xor(v, 32);
        if (ql == 0) atomicAdd(&bins[(ck << 3) + h], v);
      }
    }
  }
  __syncthreads();

  // write Wn[g][h][c] from bins[c][h]
  const float invn = nw ? 1.f / (float)nw : 0.f;
  for (int i = t; i < NH * VOC; i += 768) {
    int hh = i >> 7, cc = i & 127;
    Wn[(size_t)g * 1024 + i] = bins[(cc << 3) + hh] * invn;
  }
}

extern "C" void kernel_launch(void* const* d_in, const int* in_sizes, int n_in,
                              void* d_out, int out_size, void* d_ws, size_t ws_size,
                              hipStream_t stream) {
  const int*   inputs  = (const int*)d_in[0];
  const int*   n_words = (const int*)d_in[1];
  const float* emb     = (const float*)d_in[3];
  const float* Wq      = (const float*)d_in[4];
  const float* Wk      = (const float*)d_in[5];
  const float* Wv      = (const float*)d_in[6];
  const float* Wo      = (const float*)d_in[7];
  const float* W1      = (const float*)d_in[8];
  const float* W2      = (const float*)d_in[9];
  float* out = (float*)d_out;

  // workspace layout (floats), ~27.5 MB
  float* ws  = (float*)d_ws;
  float* ES  = ws;                      // 458752: [EQ|EK|EV|WF]
  float* BIG = ws + 458752;             // 4194304: split-K partials
  float* Wn  = BIG;                     // alias: live range disjoint from BIG uses
  float* TAB = ws + 4653056;            // 131072: exp table [c1][c2][h]
  float* NP  = ws + 4784128;            // 2048*512
  float* H1  = ws + 5832704;            // 2048*512
  int*  OFFS = (int*)(ws + 6881280);    // 2049 ints

  k_scan<<<1, 256, 0, stream>>>(n_words, OFFS);
  // stage-1 fused GEMMs, split-K=4 -> 448 blocks
  k_stage1<4><<<dim3(112, 4), 256, 0, stream>>>(emb, Wq, Wk, Wv, Wo, W1, BIG);
  k_reduce<0, 4><<<S1_LEN / 4 / 256, 256, 0, stream>>>(BIG, ES, S1_LEN / 4, S1_LEN / 4);
  // exp(qk) table from EQ, EK (pad rows/cols zeroed)
  k_qk_tab<<<dim3(VOC, NH), 128, 0, stream>>>(ES, ES + 65536, TAB);
  // per-name attention-mass histogram (BIG free here; Wn aliases it)
  k_bins<<<GNAMES, 768, 0, stream>>>(inputs, OFFS, TAB, Wn);
  // NP = per-head Wn @ EV
  k_npool<<<dim3(GNAMES / 64, NH), 256, 0, stream>>>(Wn, ES + 131072, NP);
  // h1 = tanh(NP @ WF), split-K=4 -> 1024 blocks, tanh in reduce (overwrites BIG/Wn)
  k_gemm64<0><<<dim3(8, 32, 4), 256, 0, stream>>>(NP, ES + 196608, BIG, 2048, 512, 512, 128);
  k_reduce<1, 4><<<(GNAMES * DIM) / 4 / 256, 256, 0, stream>>>(BIG, H1, (GNAMES * DIM) / 4, (GNAMES * DIM) / 4);
  // out = tanh(H1 @ W2), split-K=4 -> 512 blocks, tanh in reduce
  k_gemm64<0><<<dim3(4, 32, 4), 256, 0, stream>>>(H1, W2, BIG, 2048, F2, 512, 128);
  k_reduce<1, 4><<<(GNAMES * F2) / 4 / 256, 256, 0, stream>>>(BIG, out, (GNAMES * F2) / 4, (GNAMES * F2) / 4);
}

// Round 8
// 108.412 us; speedup vs baseline: 1.3184x; 1.3184x over previous
//
#include <hip/hip_runtime.h>
#include <math.h>

// Problem constants (fixed by setup_inputs)
#define NWORDS 8192
#define LW     24
#define VOC    128
#define DIM    512
#define NH     8
#define DKH    64
#define GNAMES 2048
#define F2     256

// stage-1 fused output layout (floats): [EQ 65536 | EK 65536 | EV 65536 | WF 262144]
#define S1_LEN 458752

// =================== double-buffered 64x64 fp32 GEMM body ====================
// 256 threads, BK=16, 4x4 register tile, one barrier per K-step.
// K_ is used as lda, N_ as ldb only.
#define GEMM_BODY(A_, B_, K_, N_, m0_, n0_, kbeg_, kchunk_)                         \
  __shared__ float As[2][16][68];                                                   \
  __shared__ float Bs[2][16][68];                                                   \
  const int t = threadIdx.x, tx = t & 15, ty = t >> 4;                              \
  float acc[4][4] = {};                                                             \
  float ra[4], rb[4];                                                               \
  _Pragma("unroll")                                                                 \
  for (int i = 0; i < 4; ++i) { int idx = t + 256 * i;                              \
    ra[i] = A_[(size_t)(m0_ + (idx >> 4)) * K_ + kbeg_ + (idx & 15)]; }             \
  _Pragma("unroll")                                                                 \
  for (int i = 0; i < 4; ++i) { int idx = t + 256 * i;                              \
    rb[i] = B_[(size_t)(kbeg_ + (idx >> 6)) * N_ + n0_ + (idx & 63)]; }             \
  _Pragma("unroll")                                                                 \
  for (int i = 0; i < 4; ++i) { int idx = t + 256 * i; As[0][idx & 15][idx >> 4] = ra[i]; } \
  _Pragma("unroll")                                                                 \
  for (int i = 0; i < 4; ++i) { int idx = t + 256 * i; Bs[0][idx >> 6][idx & 63] = rb[i]; } \
  __syncthreads();                                                                  \
  int buf = 0;                                                                      \
  for (int k0 = kbeg_; k0 < kbeg_ + kchunk_; k0 += 16) {                            \
    const bool more = (k0 + 16 < kbeg_ + kchunk_);                                  \
    if (more) {                                                                     \
      _Pragma("unroll")                                                             \
      for (int i = 0; i < 4; ++i) { int idx = t + 256 * i;                          \
        ra[i] = A_[(size_t)(m0_ + (idx >> 4)) * K_ + (k0 + 16) + (idx & 15)]; }     \
      _Pragma("unroll")                                                             \
      for (int i = 0; i < 4; ++i) { int idx = t + 256 * i;                          \
        rb[i] = B_[(size_t)(k0 + 16 + (idx >> 6)) * N_ + n0_ + (idx & 63)]; }       \
    }                                                                               \
    _Pragma("unroll")                                                               \
    for (int k = 0; k < 16; ++k) {                                                  \
      float a[4], b[4];                                                             \
      _Pragma("unroll")                                                             \
      for (int i = 0; i < 4; ++i) a[i] = As[buf][k][ty * 4 + i];                    \
      _Pragma("unroll")                                                             \
      for (int j = 0; j < 4; ++j) b[j] = Bs[buf][k][tx * 4 + j];                    \
      _Pragma("unroll")                                                             \
      for (int i = 0; i < 4; ++i)                                                   \
        _Pragma("unroll")                                                           \
        for (int j = 0; j < 4; ++j) acc[i][j] += a[i] * b[j];                       \
    }                                                                               \
    if (more) {                                                                     \
      _Pragma("unroll")                                                             \
      for (int i = 0; i < 4; ++i) { int idx = t + 256 * i; As[buf ^ 1][idx & 15][idx >> 4] = ra[i]; } \
      _Pragma("unroll")                                                             \
      for (int i = 0; i < 4; ++i) { int idx = t + 256 * i; Bs[buf ^ 1][idx >> 6][idx & 63] = rb[i]; } \
      __syncthreads();                                                              \
      buf ^= 1;                                                                     \
    }                                                                               \
  }

// ---- stage-1 fused GEMM: EQ/EK/EV (128x512) + WF=Wo@W1 (512x512), all K=512 ----
template<int NSPLIT>
__global__ __launch_bounds__(256) void k_stage1(const float* __restrict__ emb,
                                                const float* __restrict__ Wq,
                                                const float* __restrict__ Wk,
                                                const float* __restrict__ Wv,
                                                const float* __restrict__ Wo,
                                                const float* __restrict__ W1,
                                                float* __restrict__ P) {
  const int tid = blockIdx.x, s = blockIdx.y;
  const float *A, *B;
  int coff, m0, n0;
  if (tid < 48) {
    const int g = tid >> 4, mt = tid & 15;
    A = emb;
    B = (g == 0) ? Wq : ((g == 1) ? Wk : Wv);
    coff = g * 65536;
    m0 = (mt >> 3) * 64; n0 = (mt & 7) * 64;
  } else {
    const int id = tid - 48;
    A = Wo; B = W1; coff = 3 * 65536;
    m0 = (id >> 3) * 64; n0 = (id & 7) * 64;
  }
  const int kchunk = 512 / NSPLIT, kbeg = s * kchunk;
  GEMM_BODY(A, B, 512, 512, m0, n0, kbeg, kchunk)
  float* Cp = P + (size_t)s * S1_LEN + coff;
  #pragma unroll
  for (int i = 0; i < 4; ++i) {
    float4 v = make_float4(acc[i][0], acc[i][1], acc[i][2], acc[i][3]);
    *(float4*)&Cp[(size_t)(m0 + ty * 4 + i) * 512 + n0 + tx * 4] = v;
  }
}

// ---- generic GEMM: C = A@B partials over gridDim.z ----
template<int ACT>
__global__ __launch_bounds__(256) void k_gemm64(const float* __restrict__ A,
                                                const float* __restrict__ B,
                                                float* __restrict__ C,
                                                int M, int N, int K, int kchunk) {
  const int m0 = blockIdx.y * 64, n0 = blockIdx.x * 64;
  const int kbeg = blockIdx.z * kchunk;
  GEMM_BODY(A, B, K, N, m0, n0, kbeg, kchunk)
  float* Cp = C + (size_t)blockIdx.z * M * N;
  #pragma unroll
  for (int i = 0; i < 4; ++i) {
    float4 v = make_float4(acc[i][0], acc[i][1], acc[i][2], acc[i][3]);
    if (ACT) { v.x = tanhf(v.x); v.y = tanhf(v.y); v.z = tanhf(v.z); v.w = tanhf(v.w); }
    *(float4*)&Cp[(size_t)(m0 + ty * 4 + i) * N + n0 + tx * 4] = v;
  }
}

// ---- name-pool GEMM: NP[m, h*64+n] = sum_c Wn[m][h*128+c] * EV[c][h*64+n] ----
__global__ __launch_bounds__(256) void k_npool(const float* __restrict__ Wn,
                                               const float* __restrict__ EV,
                                               float* __restrict__ NP) {
  const int m0 = blockIdx.x * 64, h = blockIdx.y;
  const float* A2 = Wn + (size_t)m0 * 1024 + h * 128;   // lda 1024
  const float* B2 = EV + h * 64;                        // ldb 512
  GEMM_BODY(A2, B2, 1024, 512, 0, 0, 0, 128)
  #pragma unroll
  for (int i = 0; i < 4; ++i) {
    float4 v = make_float4(acc[i][0], acc[i][1], acc[i][2], acc[i][3]);
    *(float4*)&NP[(size_t)(m0 + ty * 4 + i) * 512 + h * 64 + tx * 4] = v;
  }
}

// ---- sum S partial buffers, optional tanh ----
template<int ACT, int S>
__global__ __launch_bounds__(256) void k_reduce(const float* __restrict__ P,
                                                float* __restrict__ O,
                                                int len4, int stride4) {
  const int i = blockIdx.x * 256 + threadIdx.x;
  if (i >= len4) return;
  const float4* P4 = (const float4*)P;
  float4 a = P4[i];
  #pragma unroll
  for (int s = 1; s < S; ++s) {
    float4 b = P4[(size_t)s * stride4 + i];
    a.x += b.x; a.y += b.y; a.z += b.z; a.w += b.w;
  }
  if (ACT) { a.x = tanhf(a.x); a.y = tanhf(a.y); a.z = tanhf(a.z); a.w = tanhf(a.w); }
  ((float4*)O)[i] = a;
}

// ---- exp(qk) table, zeroed on pad rows/cols: ETAB[c1][c2][h] ----
__global__ __launch_bounds__(128) void k_qk_tab(const float* __restrict__ EQ,
                                                const float* __restrict__ EK,
                                                float* __restrict__ etab) {
  const int c1 = blockIdx.x, h = blockIdx.y, c2 = threadIdx.x;
  __shared__ float qrow[DKH];
  if (threadIdx.x < DKH) qrow[threadIdx.x] = EQ[c1 * DIM + h * DKH + threadIdx.x];
  __syncthreads();
  const float* krow = EK + c2 * DIM + h * DKH;
  float acc = 0.f;
  #pragma unroll
  for (int d = 0; d < DKH; ++d) acc += qrow[d] * krow[d];
  float e = (c1 != 0 && c2 != 0) ? __expf(acc * 0.125f) : 0.f;
  etab[((size_t)c1 * VOC + c2) * NH + h] = e;
}

// ---- exclusive scan of n_words ----
__global__ __launch_bounds__(256) void k_scan(const int* __restrict__ nw, int* __restrict__ offs) {
  __shared__ int part[256];
  const int t = threadIdx.x;
  int v[8]; int s = 0;
  #pragma unroll
  for (int i = 0; i < 8; ++i) { v[i] = nw[t * 8 + i]; s += v[i]; }
  part[t] = s;
  __syncthreads();
  if (t == 0) {
    int a = 0;
    for (int i = 0; i < 256; ++i) { int x = part[i]; part[i] = a; a += x; }
    offs[GNAMES] = a;
  }
  __syncthreads();
  int a = part[t];
  #pragma unroll
  for (int i = 0; i < 8; ++i) { offs[t * 8 + i] = a; a += v[i]; }
}

// ---- attention-mass histogram per name: Wn[g][h][c] ----
// Round-6 structure (wave = word, proven 43us) + ONE change: pass-1 rows are
// cached in registers (statically indexed under full unroll), so pass 2 is
// pure register FMA + shfl reduce -- global gathers halved (75M -> 37.7M).
// Lane l: h = l&7, qg = l>>3 owns q in {qg, qg+8, qg+16}, each with its own
// per-(q,h) softmax denominator.
__global__ __launch_bounds__(256) void k_bins(const int* __restrict__ inputs,
                                              const int* __restrict__ offs,
                                              const float* __restrict__ etab,
                                              float* __restrict__ Wn) {
  const int g = blockIdx.x, t = threadIdx.x;
  const int wv = t >> 6, l = t & 63;
  const int h = l & 7, qg = l >> 3;
  const int o0 = offs[g], o1 = offs[g + 1];
  const int nw = o1 - o0;
  __shared__ float bins[VOC * NH];  // [c][h], 4 KB

  for (int i = t; i < VOC * NH; i += 256) bins[i] = 0.f;
  __syncthreads();

  for (int wrel = wv; wrel < nw; wrel += 4) {
    const int wi = o0 + wrel;
    int c_l = (l < LW) ? inputs[(size_t)wi * LW + l] : 0;
    unsigned long long mk = __ballot(c_l != 0);
    int cnt = __popcll(mk);
    float invc = cnt ? 1.f / (float)cnt : 0.f;

    int cq0 = __shfl(c_l, qg);
    int cq1 = __shfl(c_l, qg + 8);
    int cq2 = __shfl(c_l, qg + 16);
    const float* b0 = etab + (cq0 << 10) + h;
    const float* b1 = etab + (cq1 << 10) + h;
    const float* b2 = etab + (cq2 << 10) + h;

    // pass 1: gather rows into registers, accumulate denominators
    float r0[LW], r1[LW], r2[LW];
    float d0 = 0.f, d1 = 0.f, d2 = 0.f;
    #pragma unroll
    for (int kp = 0; kp < LW; ++kp) {
      int o = __shfl(c_l, kp) << 3;
      r0[kp] = b0[o]; r1[kp] = b1[o]; r2[kp] = b2[o];
      d0 += r0[kp]; d1 += r1[kp]; d2 += r2[kp];
    }
    float i0 = cq0 ? invc / d0 : 0.f;
    float i1 = cq1 ? invc / d1 : 0.f;
    float i2 = cq2 ? invc / d2 : 0.f;

    // pass 2: register-only weighting, q-reduce, scatter to char bins
    #pragma unroll
    for (int kp = 0; kp < LW; ++kp) {
      int ck = __shfl(c_l, kp);   // wave-uniform
      if (ck) {
        float v = r0[kp] * i0 + r1[kp] * i1 + r2[kp] * i2;
        v += __shfl_xor(v, 8);
        v += __shfl_xor(v, 16);
        v += __shfl_xor(v, 32);
        if (qg == 0) atomicAdd(&bins[(ck << 3) + h], v);
      }
    }
  }
  __syncthreads();

  // write Wn[g][h][c] from bins[c][h]
  const float invn = nw ? 1.f / (float)nw : 0.f;
  for (int i = t; i < NH * VOC; i += 256) {
    int hh = i >> 7, cc = i & 127;
    Wn[(size_t)g * 1024 + i] = bins[(cc << 3) + hh] * invn;
  }
}

extern "C" void kernel_launch(void* const* d_in, const int* in_sizes, int n_in,
                              void* d_out, int out_size, void* d_ws, size_t ws_size,
                              hipStream_t stream) {
  const int*   inputs  = (const int*)d_in[0];
  const int*   n_words = (const int*)d_in[1];
  const float* emb     = (const float*)d_in[3];
  const float* Wq      = (const float*)d_in[4];
  const float* Wk      = (const float*)d_in[5];
  const float* Wv      = (const float*)d_in[6];
  const float* Wo      = (const float*)d_in[7];
  const float* W1      = (const float*)d_in[8];
  const float* W2      = (const float*)d_in[9];
  float* out = (float*)d_out;

  // workspace layout (floats), ~27.5 MB
  float* ws  = (float*)d_ws;
  float* ES  = ws;                      // 458752: [EQ|EK|EV|WF]
  float* BIG = ws + 458752;             // 4194304: split-K partials
  float* Wn  = BIG;                     // alias: live range disjoint from BIG uses
  float* TAB = ws + 4653056;            // 131072: exp table [c1][c2][h]
  float* NP  = ws + 4784128;            // 2048*512
  float* H1  = ws + 5832704;            // 2048*512
  int*  OFFS = (int*)(ws + 6881280);    // 2049 ints

  k_scan<<<1, 256, 0, stream>>>(n_words, OFFS);
  // stage-1 fused GEMMs, split-K=4 -> 448 blocks
  k_stage1<4><<<dim3(112, 4), 256, 0, stream>>>(emb, Wq, Wk, Wv, Wo, W1, BIG);
  k_reduce<0, 4><<<S1_LEN / 4 / 256, 256, 0, stream>>>(BIG, ES, S1_LEN / 4, S1_LEN / 4);
  // exp(qk) table from EQ, EK (pad rows/cols zeroed)
  k_qk_tab<<<dim3(VOC, NH), 128, 0, stream>>>(ES, ES + 65536, TAB);
  // per-name attention-mass histogram (BIG free here; Wn aliases it)
  k_bins<<<GNAMES, 256, 0, stream>>>(inputs, OFFS, TAB, Wn);
  // NP = per-head Wn @ EV
  k_npool<<<dim3(GNAMES / 64, NH), 256, 0, stream>>>(Wn, ES + 131072, NP);
  // h1 = tanh(NP @ WF), split-K=4 -> 1024 blocks, tanh in reduce (overwrites BIG/Wn)
  k_gemm64<0><<<dim3(8, 32, 4), 256, 0, stream>>>(NP, ES + 196608, BIG, 2048, 512, 512, 128);
  k_reduce<1, 4><<<(GNAMES * DIM) / 4 / 256, 256, 0, stream>>>(BIG, H1, (GNAMES * DIM) / 4, (GNAMES * DIM) / 4);
  // out = tanh(H1 @ W2), split-K=4 -> 512 blocks, tanh in reduce
  k_gemm64<0><<<dim3(4, 32, 4), 256, 0, stream>>>(H1, W2, BIG, 2048, F2, 512, 128);
  k_reduce<1, 4><<<(GNAMES * F2) / 4 / 256, 256, 0, stream>>>(BIG, out, (GNAMES * F2) / 4, (GNAMES * F2) / 4);
}